// Round 10
// baseline (204.703 us; speedup 1.0000x reference)
//
#include <hip/hip_runtime.h>
#include <hip/hip_bf16.h>
#include <math.h>
#include <stdint.h>
#include <string.h>

#define TSEQ 2048
#define DMODEL 1024
#define NH 16
#define HD 64
#define BROWS 4096   // b*t
#define BH 32        // b*h

typedef __attribute__((ext_vector_type(8))) short short8;
typedef __attribute__((ext_vector_type(4))) float floatx4;

#define MFMA16 __builtin_amdgcn_mfma_f32_16x16x32_bf16
// 3-bit chunk-XOR swizzle on 64-short (128 B) rows
#define SWZ8(r, q) ((((q) ^ ((r) & 7)) * 8))

#define QSCALE 0.18033688011112042f   // 0.125 * log2(e); p = exp2(s) = exp(s/log2e)

__device__ __forceinline__ unsigned short bf16_rne(float f) {
    uint32_t u = __float_as_uint(f);
    u += 0x7FFFu + ((u >> 16) & 1u);
    return (unsigned short)(u >> 16);
}

__device__ __forceinline__ uint32_t pack_bf16x2(float a, float b) {
    __hip_bfloat162 h = __float22bfloat162_rn(float2{a, b});
    uint32_t r;
    memcpy(&r, &h, 4);
    return r;
}

__device__ __forceinline__ void split_bf16(float f, short& hi, short& lo) {
    uint32_t u = __float_as_uint(f);
    hi = (short)(u >> 16);
    float hif = __uint_as_float(u & 0xFFFF0000u);
    lo = (short)bf16_rne(f - hif);
}

__device__ __forceinline__ void async16(const void* g, void* l) {
    __builtin_amdgcn_global_load_lds(
        (__attribute__((address_space(1))) const uint32_t*)g,
        (__attribute__((address_space(3))) uint32_t*)l, 16, 0, 0);
}

// ---------------------------------------------------------------------------
// Fused pack (unchanged)
// ---------------------------------------------------------------------------
struct PackArgs {
    const float4* x;
    ushort4* xb;
    const float4* w[3];   // Wq, Wk, Wv
    ushort4* wb[3];
    const float4* wo;
    ushort4* woh;
    ushort4* wol;
};
__global__ __launch_bounds__(256) void pack_all(PackArgs a) {
    const int y = blockIdx.y;
    const int base = blockIdx.x * 256 + threadIdx.x;
    if (y == 0) {
#pragma unroll
        for (int it = 0; it < 4; ++it) {
            int i = base + it * 262144;
            float4 f = a.x[i];
            a.xb[i] = make_ushort4(bf16_rne(f.x), bf16_rne(f.y),
                                   bf16_rne(f.z), bf16_rne(f.w));
        }
    } else if (y <= 3) {
        int w = y - 1;
        float4 f = a.w[w][base];
        a.wb[w][base] = make_ushort4(bf16_rne(f.x), bf16_rne(f.y),
                                     bf16_rne(f.z), bf16_rne(f.w));
    } else {
        float4 f = a.wo[base];
        short h0, l0, h1, l1, h2, l2, h3, l3;
        split_bf16(f.x, h0, l0); split_bf16(f.y, h1, l1);
        split_bf16(f.z, h2, l2); split_bf16(f.w, h3, l3);
        a.woh[base] = make_ushort4(h0, h1, h2, h3);
        a.wol[base] = make_ushort4(l0, l1, l2, l3);
    }
}

// ---------------------------------------------------------------------------
// Fused QKV single-bf16 GEMM (unchanged from R9). 128x128, BK=64, 768 blocks.
// ---------------------------------------------------------------------------
__global__ __launch_bounds__(256) void gemm_qkv(
    const short* __restrict__ Xb,
    const short* __restrict__ Bq, const short* __restrict__ Bk,
    const short* __restrict__ Bv,
    short* __restrict__ Qo, short* __restrict__ Ko, short* __restrict__ Vo) {
    __shared__ short sA[128 * 64];
    __shared__ short sB[128 * 64];
    const int K = DMODEL;

    const int tid = threadIdx.x;
    const int lane = tid & 63, wave = tid >> 6;
    const int quad = lane >> 4, col = lane & 15;
    const int m0 = blockIdx.y * 128, n0 = blockIdx.x * 128;
    const int which = n0 >> 10;
    const int nn0 = n0 & 1023;
    const int wm = wave >> 1, wn = wave & 1;

    const short* B = (which == 0) ? Bq : (which == 1) ? Bk : Bv;
    const short* Asrc = Xb + (size_t)m0 * K;
    const short* Bsrc = B + (size_t)nn0 * K;

    const int srow = lane >> 3;
    const int soff = (((lane & 7) ^ srow) * 8);

    floatx4 acc[4][4] = {};

    for (int k0 = 0; k0 < K; k0 += 64) {
        __syncthreads();
#pragma unroll
        for (int j = 0; j < 8; ++j) {
            int idx = wave * 8 + j;
            int sub = idx & 15;
            const short* s = (idx < 16) ? Asrc : Bsrc;
            short* d = (idx < 16) ? sA : sB;
            async16(s + (size_t)(sub * 8 + srow) * K + k0 + soff, d + sub * 512);
        }
        __syncthreads();

#pragma unroll
        for (int s2 = 0; s2 < 2; ++s2) {
            short8 a_b[4], b_b[4];
#pragma unroll
            for (int mi = 0; mi < 4; ++mi) {
                int r = wm * 64 + mi * 16 + col;
                a_b[mi] = *(const short8*)&sA[r * 64 + SWZ8(r, s2 * 4 + quad)];
            }
#pragma unroll
            for (int ni = 0; ni < 4; ++ni) {
                int r = wn * 64 + ni * 16 + col;
                b_b[ni] = *(const short8*)&sB[r * 64 + SWZ8(r, s2 * 4 + quad)];
            }
            if (which == 2) {
#pragma unroll
                for (int mi = 0; mi < 4; ++mi)
#pragma unroll
                    for (int ni = 0; ni < 4; ++ni)
                        acc[mi][ni] = MFMA16(a_b[mi], b_b[ni], acc[mi][ni], 0, 0, 0);
            } else {
#pragma unroll
                for (int mi = 0; mi < 4; ++mi)
#pragma unroll
                    for (int ni = 0; ni < 4; ++ni)
                        acc[mi][ni] = MFMA16(b_b[ni], a_b[mi], acc[mi][ni], 0, 0, 0);
            }
        }
    }

    const int mb = m0 + wm * 64;
    const int nlb = nn0 + wn * 64;
    if (which == 2) {
        // V^T [bh][hd][t], kappa-permuted window position + chunk-XOR swizzle
#pragma unroll
        for (int ni = 0; ni < 4; ++ni) {
            int n = nlb + ni * 16 + col;
            int h = n >> 6, hd = n & 63;
#pragma unroll
            for (int mi = 0; mi < 4; ++mi) {
                int m4 = mb + mi * 16 + quad * 4;
                int b = m4 >> 11, t0 = m4 & 2047;
                int sw = (t0 & 32) | ((t0 & 12) << 1) | ((t0 & 16) >> 2);
                int tsw = (t0 & ~63) | ((((sw >> 3) ^ (hd & 7)) << 3) | (sw & 7));
                size_t row = ((size_t)(b * NH + h) * HD + hd) * TSEQ;
                *(ushort4*)&Vo[row + tsw] =
                    make_ushort4(bf16_rne(acc[mi][ni][0]), bf16_rne(acc[mi][ni][1]),
                                 bf16_rne(acc[mi][ni][2]), bf16_rne(acc[mi][ni][3]));
            }
        }
    } else {
        short* O = (which == 0) ? Qo : Ko;
        const float sc = (which == 0) ? QSCALE : 1.0f;
#pragma unroll
        for (int mi = 0; mi < 4; ++mi) {
            int m = mb + mi * 16 + col;
            int b = m >> 11, t = m & 2047;
#pragma unroll
            for (int ni = 0; ni < 4; ++ni) {
                int n = nlb + ni * 16 + quad * 4;
                int h = n >> 6, hd = n & 63;
                int hds = (which == 1) ? ((((hd >> 3) ^ (t & 7)) << 3) | (hd & 7)) : hd;
                size_t idx = ((size_t)(b * NH + h) * TSEQ + t) * HD + hds;
                *(ushort4*)&O[idx] =
                    make_ushort4(bf16_rne(acc[mi][ni][0] * sc), bf16_rne(acc[mi][ni][1] * sc),
                                 bf16_rne(acc[mi][ni][2] * sc), bf16_rne(acc[mi][ni][3] * sc));
            }
        }
    }
}

// ---------------------------------------------------------------------------
// Flash attention, no-sP, KEY-SPLIT x2. Grid (16 qt, 32 bh, 2 half) = 1024
// blocks (4/CU). Unnormalized softmax is associative over key halves: each
// block emits partial O (fp32) and partial l; combine kernel normalizes.
// ---------------------------------------------------------------------------
__global__ __launch_bounds__(512) void attn_bf16(
    const short* __restrict__ Qb, const short* __restrict__ Kb,
    const short* __restrict__ Vb, float* __restrict__ Op,
    float* __restrict__ lp) {
    __shared__ short sK[2][64 * 64];
    __shared__ short sV[2][64 * 64];

    const int tid = threadIdx.x;
    const int lane = tid & 63, wave = tid >> 6;
    const int quad = lane >> 4, col = lane & 15;
    const int qt = blockIdx.x, bh = blockIdx.y, half = blockIdx.z;
    const size_t bhoff = (size_t)bh * TSEQ * HD;

    // Q as B-operand frags: B[n=q=col][k=quad*8+j]
    const size_t qrow = (size_t)(qt * 128 + wave * 16 + col) * HD;
    short8 qf[2];
#pragma unroll
    for (int c = 0; c < 2; ++c)
        qf[c] = *(const short8*)&Qb[bhoff + qrow + c * 32 + quad * 8];

    const int srow = lane >> 3;
    const int schunk = (lane & 7) * 8;   // K/V globally pre-swizzled

    float l_r = 0.f;        // per-lane: q = col
    floatx4 O[4] = {};      // O^T: hd = ni*16 + quad*4 + r, q = col

    for (int kt = half * 8; kt < half * 8 + 8; ++kt) {
        __syncthreads();
#pragma unroll
        for (int j = 0; j < 4; ++j) {
            int n = wave * 4 + j;          // 0..31
            int isv = n >> 4;
            int tile = (n >> 3) & 1;
            int sub = n & 7;
            if (!isv) {
                async16(Kb + bhoff + (size_t)(kt * 128 + tile * 64 + sub * 8 + srow) * HD + schunk,
                        &sK[tile][sub * 512]);
            } else {
                async16(Vb + bhoff + (size_t)(sub * 8 + srow) * TSEQ + kt * 128 + tile * 64 + schunk,
                        &sV[tile][sub * 512]);
            }
        }
        __syncthreads();

#pragma unroll
        for (int u = 0; u < 2; ++u) {
            // S^T[key][q]: A = K (m=key), B = Q (n=q=col)
            floatx4 s[4] = {};
#pragma unroll
            for (int k4 = 0; k4 < 4; ++k4) {
                int r = k4 * 16 + col;
#pragma unroll
                for (int c = 0; c < 2; ++c) {
                    int ch = (((c * 4 + quad) ^ (r & 7)) << 3);
                    short8 kf = *(const short8*)&sK[u][r * 64 + ch];
                    s[k4] = MFMA16(kf, qf[c], s[k4], 0, 0, 0);
                }
            }

            // p = 2^s in registers; per-lane l
            float p[4][4];
#pragma unroll
            for (int k4 = 0; k4 < 4; ++k4)
#pragma unroll
                for (int r4 = 0; r4 < 4; ++r4) {
                    p[k4][r4] = __builtin_amdgcn_exp2f(s[k4][r4]);
                    l_r += p[k4][r4];
                }

            // O^T += MFMA(V^T, P): pf built directly from registers (kappa order)
#pragma unroll
            for (int c = 0; c < 2; ++c) {
                union { short8 v; uint32_t w[4]; } pf;
                pf.w[0] = pack_bf16x2(p[2 * c][0], p[2 * c][1]);
                pf.w[1] = pack_bf16x2(p[2 * c][2], p[2 * c][3]);
                pf.w[2] = pack_bf16x2(p[2 * c + 1][0], p[2 * c + 1][1]);
                pf.w[3] = pack_bf16x2(p[2 * c + 1][2], p[2 * c + 1][3]);
#pragma unroll
                for (int ni = 0; ni < 4; ++ni) {
                    int r = ni * 16 + col;   // hd row in sV
                    int ch = (((c * 4 + quad) ^ (r & 7)) << 3);
                    short8 vf = *(const short8*)&sV[u][r * 64 + ch];
                    O[ni] = MFMA16(vf, pf.v, O[ni], 0, 0, 0);
                }
            }
        }
    }

    // partial l: reduce over quad partners; partial O: fp32 stores
    float t = l_r;
    t += __shfl_xor(t, 16);
    t += __shfl_xor(t, 32);

    const int trow = qt * 128 + wave * 16 + col;
    const size_t pbase = ((size_t)(half * BH + bh) * TSEQ + trow) * HD;
#pragma unroll
    for (int ni = 0; ni < 4; ++ni)
        *(floatx4*)&Op[pbase + ni * 16 + quad * 4] = O[ni];
    if (quad == 0)
        lp[(size_t)(half * BH + bh) * TSEQ + trow] = t;
}

// ---------------------------------------------------------------------------
// Combine key-split partials: ctx = (O0+O1)/(l0+l1) -> bf16 [b][t][d].
// 1M threads, 16 threads per (bh,t), 4 hd each.
// ---------------------------------------------------------------------------
__global__ __launch_bounds__(256) void attn_combine(
    const float* __restrict__ Op, const float* __restrict__ lp,
    short* __restrict__ Cb) {
    const int id = blockIdx.x * 256 + threadIdx.x;   // 0 .. 2^20-1
    const int hd4 = id & 15;
    const int t = (id >> 4) & 2047;
    const int bh = id >> 15;
    const size_t HALF = (size_t)BH * TSEQ * HD;

    const size_t base = ((size_t)bh * TSEQ + t) * HD + hd4 * 4;
    float4 o0 = *(const float4*)&Op[base];
    float4 o1 = *(const float4*)&Op[HALF + base];
    float l0 = lp[(size_t)bh * TSEQ + t];
    float l1 = lp[(size_t)BH * TSEQ + (size_t)bh * TSEQ + t];
    float inv = 1.0f / (l0 + l1);

    const int b = bh >> 4, h = bh & 15;
    uint2 pk;
    pk.x = pack_bf16x2((o0.x + o1.x) * inv, (o0.y + o1.y) * inv);
    pk.y = pack_bf16x2((o0.z + o1.z) * inv, (o0.w + o1.w) * inv);
    *(uint2*)&Cb[(size_t)(b * TSEQ + t) * DMODEL + h * HD + hd4 * 4] = pk;
}

// ---------------------------------------------------------------------------
// Out-proj 2-term, operand-flipped (unchanged). 128x64, BK=64.
// ---------------------------------------------------------------------------
__global__ __launch_bounds__(256) void gemm_out(
    const short* __restrict__ Ab,
    const short* __restrict__ Bh, const short* __restrict__ Bl,
    const float* __restrict__ bias, float* __restrict__ Of) {
    __shared__ short sA[128 * 64];
    __shared__ short sBh[64 * 64];
    __shared__ short sBl[64 * 64];
    const int K = DMODEL, N = DMODEL;

    const int tid = threadIdx.x;
    const int lane = tid & 63, wave = tid >> 6;
    const int quad = lane >> 4, col = lane & 15;
    const int m0 = blockIdx.y * 128, n0 = blockIdx.x * 64;
    const int wm = wave >> 1, wn = wave & 1;

    const short* Asrc = Ab + (size_t)m0 * K;
    const short* Bhsrc = Bh + (size_t)n0 * K;
    const short* Blsrc = Bl + (size_t)n0 * K;
    const int srow = lane >> 3;
    const int soff = (((lane & 7) ^ srow) * 8);

    floatx4 acc[4][2] = {};

    for (int k0 = 0; k0 < K; k0 += 64) {
        __syncthreads();
#pragma unroll
        for (int j = 0; j < 8; ++j) {
            int idx = wave * 8 + j;
            int buf = (idx < 16) ? 0 : (idx < 24) ? 1 : 2;
            int sub = (buf == 0) ? idx : (buf == 1) ? idx - 16 : idx - 24;
            const short* s = (buf == 0) ? Asrc : (buf == 1) ? Bhsrc : Blsrc;
            short* d = (buf == 0) ? sA : (buf == 1) ? sBh : sBl;
            async16(s + (size_t)(sub * 8 + srow) * K + k0 + soff, d + sub * 512);
        }
        __syncthreads();

#pragma unroll
        for (int s2 = 0; s2 < 2; ++s2) {
            short8 a_b[4], b_h[2], b_l[2];
#pragma unroll
            for (int mi = 0; mi < 4; ++mi) {
                int r = wm * 64 + mi * 16 + col;
                a_b[mi] = *(const short8*)&sA[r * 64 + SWZ8(r, s2 * 4 + quad)];
            }
#pragma unroll
            for (int ni = 0; ni < 2; ++ni) {
                int r = wn * 32 + ni * 16 + col;
                b_h[ni] = *(const short8*)&sBh[r * 64 + SWZ8(r, s2 * 4 + quad)];
                b_l[ni] = *(const short8*)&sBl[r * 64 + SWZ8(r, s2 * 4 + quad)];
            }
#pragma unroll
            for (int mi = 0; mi < 4; ++mi)
#pragma unroll
                for (int ni = 0; ni < 2; ++ni) {
                    acc[mi][ni] = MFMA16(b_h[ni], a_b[mi], acc[mi][ni], 0, 0, 0);
                    acc[mi][ni] = MFMA16(b_l[ni], a_b[mi], acc[mi][ni], 0, 0, 0);
                }
        }
    }

    const int mb = m0 + wm * 64, nb = n0 + wn * 32;
#pragma unroll
    for (int mi = 0; mi < 4; ++mi) {
        int m = mb + mi * 16 + col;
#pragma unroll
        for (int ni = 0; ni < 2; ++ni) {
            int n = nb + ni * 16 + quad * 4;
            float4 bv = *(const float4*)&bias[n];
            float4 o = make_float4(acc[mi][ni][0] + bv.x, acc[mi][ni][1] + bv.y,
                                   acc[mi][ni][2] + bv.z, acc[mi][ni][3] + bv.w);
            *(float4*)&Of[(size_t)m * N + n] = o;
        }
    }
}

// ---------------------------------------------------------------------------
extern "C" void kernel_launch(void* const* d_in, const int* in_sizes, int n_in,
                              void* d_out, int out_size, void* d_ws, size_t ws_size,
                              hipStream_t stream) {
    const float* x  = (const float*)d_in[0];
    const float* Wq = (const float*)d_in[1];
    const float* Wk = (const float*)d_in[2];
    const float* Wv = (const float*)d_in[3];
    const float* Wo = (const float*)d_in[4];
    const float* bo = (const float*)d_in[5];
    float* out = (float*)d_out;

    const size_t NX = (size_t)BROWS * DMODEL;   // 4M
    const size_t NW = (size_t)DMODEL * DMODEL;  // 1M
    short* p = (short*)d_ws;
    short *xb = p;
    short *wqb = xb + NX;
    short *wkb = wqb + NW;
    short *wvb = wkb + NW;
    short *woh = wvb + NW; short *wol = woh + NW;
    short *qb = wol + NW;
    short *kb = qb + NX;
    short *vb = kb + NX;
    short *cb = vb + NX;
    float *Op = (float*)(cb + NX);                       // 2*BH*TSEQ*HD fp32 = 33.6 MB
    float *lp = Op + (size_t)2 * BH * TSEQ * HD;         // 2*BH*TSEQ fp32

    PackArgs pa;
    pa.x = (const float4*)x; pa.xb = (ushort4*)xb;
    pa.w[0] = (const float4*)Wq; pa.wb[0] = (ushort4*)wqb;
    pa.w[1] = (const float4*)Wk; pa.wb[1] = (ushort4*)wkb;
    pa.w[2] = (const float4*)Wv; pa.wb[2] = (ushort4*)wvb;
    pa.wo = (const float4*)Wo; pa.woh = (ushort4*)woh; pa.wol = (ushort4*)wol;
    pack_all<<<dim3(1024, 5), dim3(256), 0, stream>>>(pa);

    gemm_qkv<<<dim3(3 * DMODEL / 128, BROWS / 128), dim3(256), 0, stream>>>(
        xb, wqb, wkb, wvb, qb, kb, vb);

    attn_bf16<<<dim3(TSEQ / 128, BH, 2), dim3(512), 0, stream>>>(qb, kb, vb, Op, lp);

    attn_combine<<<dim3(4096), dim3(256), 0, stream>>>(Op, lp, cb);

    gemm_out<<<dim3(DMODEL / 64, BROWS / 128), dim3(256), 0, stream>>>(cb, woh, wol, bo, out);
}